// Round 5
// baseline (396.324 us; speedup 1.0000x reference)
//
#include <hip/hip_runtime.h>
#include <hip/hip_bf16.h>

#define BSZ 4
#define SEQ 2048
#define DMODEL 1024
#define DINNER 2048
#define DSTATE 64
#define NH 32
#define HD 64
#define CKL 64            // chunk length
#define NCH 32            // chunks per sequence
#define CONVD 2176
#define DPROJ 4256
#define N1 4224           // GEMM1 N = DINNER + CONVD = 22*192
#define MTOT 8192         // BSZ*SEQ
#define YSTR 72           // LDS row stride (bf16): 144 B, keeps 16B alignment

typedef __hip_bfloat16 bf16;
typedef __attribute__((ext_vector_type(8))) short short8;   // 8 bf16 (4 VGPRs)
typedef __attribute__((ext_vector_type(4))) short short4_;  // 8 bytes
typedef __attribute__((ext_vector_type(4))) float f32x4;

__device__ __forceinline__ float sigmoidf_(float x) { return 1.0f / (1.0f + __expf(-x)); }
__device__ __forceinline__ float bits2f(short s) { return __uint_as_float(((unsigned)(unsigned short)s) << 16); }
__device__ __forceinline__ short f2bits(float f) {
    bf16 h = __float2bfloat16(f);
    return *reinterpret_cast<short*>(&h);
}

__device__ __forceinline__ void gl_lds16(const bf16* g, bf16* l) {
    __builtin_amdgcn_global_load_lds((const __attribute__((address_space(1))) void*)g,
                                     (__attribute__((address_space(3))) void*)l, 16, 0, 0);
}

__device__ __forceinline__ f32x4 MF(short8 a, short8 b, f32x4 c) {
    return __builtin_amdgcn_mfma_f32_16x16x32_bf16(a, b, c, 0, 0, 0);
}

// counted s_waitcnt vmcnt(N); "memory" clobber = compiler fence.
template<int N> __device__ __forceinline__ void vmw() {
    if constexpr (N == 0)      asm volatile("s_waitcnt vmcnt(0)" ::: "memory");
    else if constexpr (N == 3) asm volatile("s_waitcnt vmcnt(3)" ::: "memory");
    else if constexpr (N == 6) asm volatile("s_waitcnt vmcnt(6)" ::: "memory");
    else                       asm volatile("s_waitcnt vmcnt(15)" ::: "memory");
}

// XCD-chunked locality swizzle (bijective: nwg % 8 == 0 for GEMM grids).
__device__ __forceinline__ void swzx(int& bx, int& by) {
    int nx = gridDim.x;
    int nwg = nx * gridDim.y;
    int Lr = blockIdx.y * nx + blockIdx.x;
    int L = (Lr & 7) * (nwg >> 3) + (Lr >> 3);   // contiguous chunk per XCD
    int GSZ = nx * 8;
    int g = L / GSZ, r = L - g * GSZ;
    bx = r % nx;
    by = g * 8 + r / nx;
}

// ---------------- both weight converts in one launch ----------------
__global__ void k_cvt2(const float* __restrict__ W_in, const float* __restrict__ W_out,
                       const float* __restrict__ nw, bf16* __restrict__ win_b,
                       bf16* __restrict__ wout_b) {
    int g = (blockIdx.x * 256 + threadIdx.x) * 4;
    if (g < N1 * DMODEL) {
        f32x4 f = *(const f32x4*)&W_in[g];
        short4_ o;
#pragma unroll
        for (int j = 0; j < 4; j++) o[j] = f2bits(f[j]);
        *(short4_*)&win_b[g] = o;
    } else if (g < N1 * DMODEL + DMODEL * DINNER) {
        int g2 = g - N1 * DMODEL;
        f32x4 f = *(const f32x4*)&W_out[g2];
        f32x4 w = *(const f32x4*)&nw[g2 & (DINNER - 1)];
        short4_ o;
#pragma unroll
        for (int j = 0; j < 4; j++) o[j] = f2bits(f[j] * w[j]);
        *(short4_*)&wout_b[g2] = o;
    }
}

// Shared phase scaffolding for the counted-vmcnt GEMMs.
#define BARWAIT()                                           \
    __builtin_amdgcn_s_barrier();                           \
    asm volatile("s_waitcnt lgkmcnt(0)" ::: "memory");      \
    __builtin_amdgcn_sched_barrier(0);                      \
    __builtin_amdgcn_s_setprio(1)
#define ENDPH()                                             \
    __builtin_amdgcn_s_setprio(0);                          \
    __builtin_amdgcn_s_barrier()

// =====================================================================
// GEMM1: zx[8192][4224] = A[8192][1024] * W[4224][1024]^T  (bf16 out)
// BM=256 x BN=192, BK=64, NT=16. 8 waves (2M x 4N), wave 128x48.
// 2 LDS buffers (112 KiB). 8 phases per 2 K-tiles, 12 MFMA/cluster.
// =====================================================================
__global__ __launch_bounds__(512, 2) void k_g1(const bf16* __restrict__ Ap,
                                               const bf16* __restrict__ Wp,
                                               bf16* __restrict__ Cp) {
    __shared__ __align__(16) short sA[2][16384];  // [buf][256][64]
    __shared__ __align__(16) short sB[2][12288];  // [buf][192][64]
    const int tid = threadIdx.x;
    const int lane = tid & 63, w = tid >> 6;
    const int wm = w >> 2, wn = w & 3;
    const int lr = lane & 15, lk = lane >> 4;
    int bx, by; swzx(bx, by);
    const int m0 = by * 256, n0 = bx * 192;
    const int ld = DMODEL;

    const int r8 = tid >> 3;
    const int c8 = ((tid & 7) ^ (r8 & 7)) * 8;
    const bf16* pA = Ap + (size_t)(m0 + r8) * ld + c8;
    const bf16* pB = Wp + (size_t)(n0 + r8) * ld + c8;

    auto stA = [&](int d, int t) {
#pragma unroll
        for (int h = 0; h < 2; h++)
#pragma unroll
            for (int q = 0; q < 2; q++)
                gl_lds16(pA + (size_t)(h * 128 + q * 64) * ld + t * 64,
                         (bf16*)&sA[d][h * 8192 + q * 4096 + tid * 8]);
    };
    auto stB = [&](int d, int u, int t) {
        gl_lds16(pB + (size_t)(u * 64) * ld + t * 64,
                 (bf16*)&sB[d][u * 4096 + tid * 8]);
    };

    const int c0 = (lk ^ (lr & 7)) * 8;
    const int c1 = ((lk + 4) ^ (lr & 7)) * 8;
    const int aR = (wm * 128 + lr) * 64;
    const int bR = (wn * 48 + lr) * 64;

    f32x4 acc[8][3];
#pragma unroll
    for (int i = 0; i < 8; i++)
#pragma unroll
        for (int j = 0; j < 3; j++) acc[i][j] = (f32x4){0.f, 0.f, 0.f, 0.f};
    short8 bfr[3][2], af[2][2];

#define RDA1(D, I)                                                   \
    af[0][0] = *(const short8*)&sA[D][aR + (I) * 1024 + c0];         \
    af[0][1] = *(const short8*)&sA[D][aR + (I) * 1024 + c1];         \
    af[1][0] = *(const short8*)&sA[D][aR + (I + 1) * 1024 + c0];     \
    af[1][1] = *(const short8*)&sA[D][aR + (I + 1) * 1024 + c1]
#define RDB1(D)                                                      \
    _Pragma("unroll")                                                \
    for (int jn = 0; jn < 3; ++jn) {                                 \
        bfr[jn][0] = *(const short8*)&sB[D][bR + jn * 1024 + c0];    \
        bfr[jn][1] = *(const short8*)&sB[D][bR + jn * 1024 + c1];    \
    }
#define MM1(I)                                                       \
    _Pragma("unroll")                                                \
    for (int hh = 0; hh < 2; ++hh) {                                 \
        _Pragma("unroll")                                            \
        for (int jn = 0; jn < 3; ++jn) {                             \
            acc[I][jn]     = MF(af[0][hh], bfr[jn][hh], acc[I][jn]); \
            acc[I + 1][jn] = MF(af[1][hh], bfr[jn][hh], acc[I + 1][jn]); \
        }                                                            \
    }

    stB(0, 0, 0); stB(0, 1, 0); stB(0, 2, 0); stA(0, 0);
    stB(1, 0, 1); stB(1, 1, 1); stB(1, 2, 1);
    vmw<3>();
    __builtin_amdgcn_s_barrier();

    for (int t0 = 0; t0 < 16; t0 += 2) {
        const int t1 = t0 + 1, t2 = t0 + 2, t3 = t0 + 3;
        const bool more = (t2 < 16);
        // P1
        RDB1(0); RDA1(0, 0);
        stA(1, t1);
        BARWAIT(); MM1(0); ENDPH();
        // P2
        RDA1(0, 2); if (more) stB(0, 0, t2);
        BARWAIT(); MM1(2); ENDPH();
        // P3
        RDA1(0, 4); if (more) stB(0, 1, t2);
        BARWAIT(); MM1(4); ENDPH();
        // P4
        RDA1(0, 6); if (more) stB(0, 2, t2);
        BARWAIT(); MM1(6);
        __builtin_amdgcn_s_setprio(0);
        if (more) vmw<3>(); else vmw<0>();
        __builtin_amdgcn_s_barrier();
        // P5
        RDB1(1); RDA1(1, 0);
        if (more) stA(0, t2);
        BARWAIT(); MM1(0); ENDPH();
        // P6
        RDA1(1, 2); if (more) stB(1, 0, t3);
        BARWAIT(); MM1(2); ENDPH();
        // P7
        RDA1(1, 4); if (more) stB(1, 1, t3);
        BARWAIT(); MM1(4); ENDPH();
        // P8
        RDA1(1, 6); if (more) stB(1, 2, t3);
        BARWAIT(); MM1(6);
        __builtin_amdgcn_s_setprio(0);
        if (more) vmw<3>();
        __builtin_amdgcn_s_barrier();
    }
#undef RDA1
#undef RDB1
#undef MM1

#pragma unroll
    for (int im = 0; im < 8; im++) {
        int row = m0 + wm * 128 + im * 16 + lk * 4;
#pragma unroll
        for (int jn = 0; jn < 3; jn++) {
            int col = n0 + wn * 48 + jn * 16 + lr;
            bf16* cp = Cp + (size_t)row * N1 + col;
#pragma unroll
            for (int rr = 0; rr < 4; rr++) cp[(size_t)rr * N1] = __float2bfloat16(acc[im][jn][rr]);
        }
    }
}

// =====================================================================
// GEMM2 (+fused RMSNorm): out[8192][1024] = A(zx)[8192][2048] * W[1024][2048]^T
// BM=256 x BN=128, BK=64, NT=32. 8 waves (4M x 2N), wave 64x64.
// 3 LDS buffers (144 KiB), counted vmcnt(6)/tile, 2 phases/tile.
// =====================================================================
__global__ __launch_bounds__(512, 2) void k_g2(const bf16* __restrict__ Ap,
                                               const bf16* __restrict__ Wp,
                                               float* __restrict__ Cp) {
    __shared__ __align__(16) short sA[3][16384];  // [buf][256][64]
    __shared__ __align__(16) short sB[3][8192];   // [buf][128][64]
    __shared__ float rsrow[256];
    const int tid = threadIdx.x;
    const int lane = tid & 63, w = tid >> 6;
    const int wm = w >> 1, wn = w & 1;
    const int lr = lane & 15, lk = lane >> 4;
    int bx, by; swzx(bx, by);
    const int m0 = by * 256, n0 = bx * 128;
    const int lda = N1, ldb = DINNER;

    const int r8 = tid >> 3;
    const int c8 = ((tid & 7) ^ (r8 & 7)) * 8;
    const bf16* pA = Ap + (size_t)(m0 + r8) * lda + c8;
    const bf16* pB = Wp + (size_t)(n0 + r8) * ldb + c8;

    auto stA = [&](int d, int t) {
#pragma unroll
        for (int h = 0; h < 2; h++)
#pragma unroll
            for (int q = 0; q < 2; q++)
                gl_lds16(pA + (size_t)(h * 128 + q * 64) * lda + t * 64,
                         (bf16*)&sA[d][h * 8192 + q * 4096 + tid * 8]);
    };
    auto stB = [&](int d, int t) {
#pragma unroll
        for (int q = 0; q < 2; q++)
            gl_lds16(pB + (size_t)(q * 64) * ldb + t * 64,
                     (bf16*)&sB[d][q * 4096 + tid * 8]);
    };

    const int c0 = (lk ^ (lr & 7)) * 8;
    const int c1 = ((lk + 4) ^ (lr & 7)) * 8;
    const int aR = (wm * 64 + lr) * 64;
    const int bR = (wn * 64 + lr) * 64;

    f32x4 acc[4][4];
#pragma unroll
    for (int i = 0; i < 4; i++)
#pragma unroll
        for (int j = 0; j < 4; j++) acc[i][j] = (f32x4){0.f, 0.f, 0.f, 0.f};
    float ssq[4] = {0.f, 0.f, 0.f, 0.f};
    short8 bfr[4][2], af[2][2];

#define RDA2(D, I)                                                   \
    af[0][0] = *(const short8*)&sA[D][aR + (I) * 1024 + c0];         \
    af[0][1] = *(const short8*)&sA[D][aR + (I) * 1024 + c1];         \
    af[1][0] = *(const short8*)&sA[D][aR + (I + 1) * 1024 + c0];     \
    af[1][1] = *(const short8*)&sA[D][aR + (I + 1) * 1024 + c1]
#define RDB2(D)                                                      \
    _Pragma("unroll")                                                \
    for (int jn = 0; jn < 4; ++jn) {                                 \
        bfr[jn][0] = *(const short8*)&sB[D][bR + jn * 1024 + c0];    \
        bfr[jn][1] = *(const short8*)&sB[D][bR + jn * 1024 + c1];    \
    }
#define MM2(I)                                                       \
    _Pragma("unroll")                                                \
    for (int hh = 0; hh < 2; ++hh) {                                 \
        _Pragma("unroll")                                            \
        for (int jn = 0; jn < 4; ++jn) {                             \
            acc[I][jn]     = MF(af[0][hh], bfr[jn][hh], acc[I][jn]); \
            acc[I + 1][jn] = MF(af[1][hh], bfr[jn][hh], acc[I + 1][jn]); \
        }                                                            \
    }
#define SSQ2(I)                                                      \
    _Pragma("unroll")                                                \
    for (int hh = 0; hh < 2; ++hh)                                   \
        _Pragma("unroll")                                            \
        for (int e = 0; e < 8; ++e) {                                \
            float v0 = bits2f(af[0][hh][e]), v1 = bits2f(af[1][hh][e]); \
            ssq[I] += v0 * v0; ssq[I + 1] += v1 * v1;                \
        }

    stB(0, 0); stA(0, 0);
    stB(1, 1); stA(1, 1);
    vmw<6>();
    __builtin_amdgcn_s_barrier();

    int rb = 0, sb = 2;
    for (int t = 0; t < 32; ++t) {
        const bool more = (t + 2 < 32);
        // Pa
        RDB2(rb); RDA2(rb, 0);
        if (more) stB(sb, t + 2);
        BARWAIT(); MM2(0); SSQ2(0); ENDPH();
        // Pb
        RDA2(rb, 2);
        if (more) stA(sb, t + 2);
        BARWAIT(); MM2(2); SSQ2(2);
        __builtin_amdgcn_s_setprio(0);
        if (more) vmw<6>(); else if (t + 1 < 32) vmw<0>();
        __builtin_amdgcn_s_barrier();
        rb = (rb == 2) ? 0 : rb + 1;
        sb = (sb == 2) ? 0 : sb + 1;
    }
#undef RDA2
#undef RDB2
#undef MM2
#undef SSQ2

#pragma unroll
    for (int im = 0; im < 4; im++) {
        float s = ssq[im];
        s += __shfl_down(s, 32);
        s += __shfl_down(s, 16);
        if (lane < 16) rsrow[wm * 64 + im * 16 + lane] = rsqrtf(s * (1.0f / DINNER) + 1e-5f);
    }
    __syncthreads();
#pragma unroll
    for (int im = 0; im < 4; im++) {
        int rl = wm * 64 + im * 16 + lk * 4;
        int row = m0 + rl;
#pragma unroll
        for (int rr = 0; rr < 4; rr++) {
            float s = rsrow[rl + rr];
#pragma unroll
            for (int jn = 0; jn < 4; jn++) {
                int col = n0 + wn * 64 + jn * 16 + lr;
                Cp[(size_t)(row + rr) * DMODEL + col] = acc[im][jn][rr] * s;
            }
        }
    }
}

// ---------------- fused: u row -> bf16 + dt projection (dt stored [h][t]) ----------------
__global__ __launch_bounds__(256) void k_prep(const float* __restrict__ u, const float* __restrict__ W_in,
                                              const float* __restrict__ dt_bias,
                                              bf16* __restrict__ u_b, float* __restrict__ dtt) {
    __shared__ __align__(16) float us[8 * DMODEL];
    const int t0 = blockIdx.x * 8;
    const int tid = threadIdx.x;
    const float* ur = u + (size_t)t0 * DMODEL;
    bf16* ub = u_b + (size_t)t0 * DMODEL;
#pragma unroll
    for (int i = 0; i < 8; i++) {
        int idx = (i * 256 + tid) * 4;
        f32x4 v = *(const f32x4*)&ur[idx];
        *(f32x4*)&us[idx] = v;
        short4_ o;
#pragma unroll
        for (int j = 0; j < 4; j++) o[j] = f2bits(v[j]);
        *(short4_*)&ub[idx] = o;
    }
    __syncthreads();
    const int h = tid >> 3, sub = tid & 7;
    const float* wr = W_in + (size_t)(DPROJ - NH + h) * DMODEL;
    float s[8] = {};
    for (int k = sub * 4; k < DMODEL; k += 32) {
        f32x4 w4 = *(const f32x4*)&wr[k];
#pragma unroll
        for (int rr = 0; rr < 8; rr++) {
            f32x4 u4 = *(const f32x4*)&us[rr * DMODEL + k];
            s[rr] += u4[0] * w4[0] + u4[1] * w4[1] + u4[2] * w4[2] + u4[3] * w4[3];
        }
    }
#pragma unroll
    for (int rr = 0; rr < 8; rr++) {
        s[rr] += __shfl_down(s[rr], 4, 8);
        s[rr] += __shfl_down(s[rr], 2, 8);
        s[rr] += __shfl_down(s[rr], 1, 8);
    }
    if (sub == 0) {
        float bh = dt_bias[h];
#pragma unroll
        for (int rr = 0; rr < 8; rr++) {
            float x = s[rr] + bh;
            dtt[(size_t)h * MTOT + t0 + rr] = (x > 20.f) ? x : log1pf(__expf(x));
        }
    }
}

// ---------------- dt chunk-scan precompute ----------------
// sAc[h][t] = inclusive cumsum of A*dt within chunk; sfv[h][t] = exp(tot - sAc)*dt;
// etot[(h*BSZ+b)*NCH + c] = exp(tot).
__global__ __launch_bounds__(256) void k_dts(const float* __restrict__ dtt, const float* __restrict__ A_log,
                                             float* __restrict__ sAc, float* __restrict__ sfv,
                                             float* __restrict__ etot) {
    const int h = blockIdx.x, b = blockIdx.y;
    const int tid = threadIdx.x, w = tid >> 6, lane = tid & 63;
    const float Ah = -__expf(A_log[h]);
#pragma unroll
    for (int g = 0; g < 8; g++) {
        int c = g * 4 + w;
        int t0 = b * SEQ + c * CKL;
        float dv = dtt[(size_t)h * MTOT + t0 + lane];
        float v = Ah * dv;
#pragma unroll
        for (int d = 1; d < 64; d <<= 1) { float o = __shfl_up(v, d); if (lane >= d) v += o; }
        float tot = __shfl(v, 63);
        sAc[(size_t)h * MTOT + t0 + lane] = v;
        sfv[(size_t)h * MTOT + t0 + lane] = __expf(tot - v) * dv;
        if (lane == 63) etot[(h * BSZ + b) * NCH + c] = __expf(tot);
    }
}

// ---------------- depthwise causal conv (width 4) + bias + SiLU ----------------
__global__ void k_conv(const bf16* __restrict__ zx, const float* __restrict__ cw,
                       const float* __restrict__ cb, bf16* __restrict__ xbc) {
    int g = (blockIdx.x * 256 + threadIdx.x) * 4;
    if (g >= MTOT * CONVD) return;
    int c0 = g % CONVD;
    int t = g / CONVD;
    int s = t & (SEQ - 1);
    const short* base = (const short*)(zx + (size_t)t * N1 + DINNER + c0);
    f32x4 w0 = *(const f32x4*)&cw[(c0 + 0) * 4];
    f32x4 w1 = *(const f32x4*)&cw[(c0 + 1) * 4];
    f32x4 w2 = *(const f32x4*)&cw[(c0 + 2) * 4];
    f32x4 w3 = *(const f32x4*)&cw[(c0 + 3) * 4];
    f32x4 a = *(const f32x4*)&cb[c0];
#pragma unroll
    for (int k = 0; k < 4; k++) {
        int st = s - 3 + k;
        if (st >= 0) {
            short4_ v = *(const short4_*)(base + (long)(k - 3) * N1);
            a[0] += bits2f(v[0]) * w0[k];
            a[1] += bits2f(v[1]) * w1[k];
            a[2] += bits2f(v[2]) * w2[k];
            a[3] += bits2f(v[3]) * w3[k];
        }
    }
    short4_ o;
#pragma unroll
    for (int j = 0; j < 4; j++) o[j] = f2bits(a[j] * sigmoidf_(a[j]));
    *(short4_*)&xbc[g] = o;
}

// ================= SSD pass A: chunk-local states (PARALLEL over chunks) =================
// S_loc[u][c][p][n] = sum_l sfv[l] * x[l][p] * B[l][n]   (old P4, verbatim math)
// u = (b*NH+h)*2+ph. grid (2, NH, BSZ*8): each block does 4 chunks, parity dbuf.
__global__ __launch_bounds__(256, 2) void k_ssda(const bf16* __restrict__ xbc, const float* __restrict__ sfv,
                                                 float* __restrict__ SL) {
    __shared__ __align__(16) short Bn[2][64 * YSTR];  // B^T [n][l]
    __shared__ __align__(16) short Xt[2][32 * YSTR];  // X^T [p][l]
    __shared__ float sf2[2][64];
    const int ph = blockIdx.x, h = blockIdx.y;
    const int b = blockIdx.z >> 3, cbase = (blockIdx.z & 7) * 4;
    const int tid = threadIdx.x;
    const int lane = tid & 63, w = tid >> 6;
    const int lr = lane & 15, lk = lane >> 4;
    const int xcol = h * HD + ph * 32;
    const int lrow = tid >> 2, c0 = (tid & 3) * 16, px = (tid & 3) * 8;
    const size_t u = (size_t)((b * NH + h) * 2 + ph);

    short8 rB0, rB1, rX; float rsf;
    auto load_grp = [&](int cc) {
        int rows0 = b * SEQ + cc * CKL;
        const short* rp = (const short*)(xbc + (size_t)(rows0 + lrow) * CONVD);
        rB0 = *(const short8*)&rp[DINNER + c0];
        rB1 = *(const short8*)&rp[DINNER + c0 + 8];
        rX  = *(const short8*)&rp[xcol + px];
        rsf = sfv[(size_t)h * MTOT + rows0 + lane];
    };
    auto scat = [&](int buf) {
#pragma unroll
        for (int j = 0; j < 8; j++) {
            Bn[buf][(c0 + j) * YSTR + lrow] = rB0[j];
            Bn[buf][(c0 + 8 + j) * YSTR + lrow] = rB1[j];
            Xt[buf][(px + j) * YSTR + lrow] = rX[j];
        }
        if (tid < 64) sf2[buf][tid] = rsf;
    };

    load_grp(cbase); scat(0);
    __syncthreads();
    for (int i = 0; i < 4; i++) {
        const int par = i & 1, nb = par ^ 1, c = cbase + i;
        if (i + 1 < 4) load_grp(c + 1);
        {
            int pw = w & 1, nh2 = w >> 1;
            short8 xt0 = *(const short8*)&Xt[par][(16 * pw + lr) * YSTR + lk * 8];
            short8 xt1 = *(const short8*)&Xt[par][(16 * pw + lr) * YSTR + 32 + lk * 8];
            f32x4 sa0 = *(const f32x4*)&sf2[par][lk * 8];
            f32x4 sa1 = *(const f32x4*)&sf2[par][lk * 8 + 4];
            f32x4 sb0 = *(const f32x4*)&sf2[par][32 + lk * 8];
            f32x4 sb1 = *(const f32x4*)&sf2[par][32 + lk * 8 + 4];
            short8 xd0, xd1;
#pragma unroll
            for (int j = 0; j < 4; j++) {
                xd0[j]     = f2bits(bits2f(xt0[j])     * sa0[j]);
                xd0[4 + j] = f2bits(bits2f(xt0[4 + j]) * sa1[j]);
                xd1[j]     = f2bits(bits2f(xt1[j])     * sb0[j]);
                xd1[4 + j] = f2bits(bits2f(xt1[4 + j]) * sb1[j]);
            }
            float* SLp = SL + (u * NCH + c) * (32 * 64);
#pragma unroll
            for (int j = 0; j < 2; j++) {
                int nt = 2 * nh2 + j;
                short8 b0 = *(const short8*)&Bn[par][(16 * nt + lr) * YSTR + lk * 8];
                short8 b1 = *(const short8*)&Bn[par][(16 * nt + lr) * YSTR + 32 + lk * 8];
                f32x4 sacc = MF(xd0, b0, (f32x4){0.f, 0.f, 0.f, 0.f});
                sacc = MF(xd1, b1, sacc);
#pragma unroll
                for (int rr = 0; rr < 4; rr++) {
                    int n = 16 * nt + lr;
                    int p = 16 * pw + lk * 4 + rr;
                    SLp[p * 64 + n] = sacc[rr];
                }
            }
        }
        if (i + 1 < 4) scat(nb);
        __syncthreads();
    }
}

// ================= SSD pass B: inter-chunk scan (the only serial part) =================
// prefix[c] = S_out[c-1] written as bf16 into the DEAD zx conv-tail region
// (row b*SEQ + c*64 + 2h+ph, cols [DINNER, DINNER+2048)). S = S_loc + etot*S.
__global__ __launch_bounds__(256) void k_ssdb(const float* __restrict__ SL, const float* __restrict__ etot,
                                              bf16* __restrict__ zx) {
    const int u = blockIdx.x, tid = threadIdx.x;
    const int b = u >> 6, rem = u & 63;
    const int h = rem >> 1, ph = rem & 1;
    float S[8];
#pragma unroll
    for (int j = 0; j < 8; j++) S[j] = 0.f;
    for (int c = 0; c < NCH; c++) {
        short8 o;
#pragma unroll
        for (int j = 0; j < 8; j++) o[j] = f2bits(S[j]);
        *(short8*)((short*)zx + (size_t)(b * SEQ + c * CKL + 2 * h + ph) * N1 + DINNER + tid * 8) = o;
        float ec = etot[(h * BSZ + b) * NCH + c];
        const float* slp = SL + ((size_t)u * NCH + c) * (32 * 64) + tid * 8;
        f32x4 v0 = *(const f32x4*)&slp[0];
        f32x4 v1 = *(const f32x4*)&slp[4];
#pragma unroll
        for (int j = 0; j < 4; j++) { S[j] = v0[j] + ec * S[j]; S[4 + j] = v1[j] + ec * S[4 + j]; }
    }
}

// ================= SSD pass C: Y = Y_off + Y_diag, gate, write (PARALLEL) =================
// Old P1 (Pb = prefix tile, == old Sb) + P2 + P3 + epilogue + z-gate, verbatim.
__global__ __launch_bounds__(256, 2) void k_ssdc(const bf16* __restrict__ xbc, const float* __restrict__ dtt,
                                                 const float* __restrict__ sAc, const float* __restrict__ Dp,
                                                 bf16* __restrict__ zx) {
    __shared__ __align__(16) short Ct[2][64 * YSTR];  // C [l][n]; own-wave rows reused as Y
    __shared__ __align__(16) short Bt[2][64 * YSTR];  // B [s][n]
    __shared__ __align__(16) short Xt[2][32 * YSTR];  // X^T [p][l]
    __shared__ __align__(16) short Pb[2][32 * YSTR];  // prefix state bf16 [p][n]
    __shared__ __align__(16) short Gs[4 * 16 * YSTR]; // per-wave G
    __shared__ __align__(16) float sdt2[2][64], sAc2[2][64];
    const int ph = blockIdx.x, h = blockIdx.y;
    const int b = blockIdx.z >> 3, cbase = (blockIdx.z & 7) * 4;
    const int tid = threadIdx.x;
    const int lane = tid & 63, w = tid >> 6;
    const int lr = lane & 15, lk = lane >> 4;
    const float Dh = Dp[h];
    const int xcol = h * HD + ph * 32;
    const int lrow = tid >> 2, c0 = (tid & 3) * 16, px = (tid & 3) * 8;
    const int zl = 16 * w + (lane >> 2), zp = (lane & 3) * 8;

    short8 rC0, rC1, rB0, rB1, rX, rZ, rP;
    float rsd, rsa;
    auto load_c = [&](int cc) {
        int rows0 = b * SEQ + cc * CKL;
        const short* rp = (const short*)(xbc + (size_t)(rows0 + lrow) * CONVD);
        rC0 = *(const short8*)&rp[DINNER + DSTATE + c0];
        rC1 = *(const short8*)&rp[DINNER + DSTATE + c0 + 8];
        rB0 = *(const short8*)&rp[DINNER + c0];
        rB1 = *(const short8*)&rp[DINNER + c0 + 8];
        rX  = *(const short8*)&rp[xcol + px];
        rZ  = *(const short8*)((const short*)zx + (size_t)(rows0 + zl) * N1 + xcol + zp);
        rP  = *(const short8*)((const short*)zx + (size_t)(rows0 + 2 * h + ph) * N1 + DINNER + tid * 8);
        rsd = dtt[(size_t)h * MTOT + rows0 + lane];
        rsa = sAc[(size_t)h * MTOT + rows0 + lane];
    };
    auto scat = [&](int buf) {
        *(short8*)&Ct[buf][lrow * YSTR + c0] = rC0;
        *(short8*)&Ct[buf][lrow * YSTR + c0 + 8] = rC1;
        *(short8*)&Bt[buf][lrow * YSTR + c0] = rB0;
        *(short8*)&Bt[buf][lrow * YSTR + c0 + 8] = rB1;
#pragma unroll
        for (int j = 0; j < 8; j++) Xt[buf][(px + j) * YSTR + lrow] = rX[j];
        *(short8*)&Pb[buf][(tid >> 3) * YSTR + (tid & 7) * 8] = rP;
        if (tid < 64) { sdt2[buf][tid] = rsd; sAc2[buf][tid] = rsa; }
    };

    load_c(cbase); scat(0);
    __syncthreads();
    for (int i = 0; i < 4; i++) {
        const int par = i & 1, nb = par ^ 1, c = cbase + i;
        const int rows0 = b * SEQ + c * CKL;
        short8 zcur = rZ;
        if (i + 1 < 4) load_c(c + 1);

        short8 cf0 = *(const short8*)&Ct[par][(16 * w + lr) * YSTR + lk * 8];
        short8 cf1 = *(const short8*)&Ct[par][(16 * w + lr) * YSTR + 32 + lk * 8];
        // P1: Y_off = C * prefix^T
        f32x4 acc[2];
#pragma unroll
        for (int t = 0; t < 2; t++) {
            short8 s0 = *(const short8*)&Pb[par][(16 * t + lr) * YSTR + lk * 8];
            short8 s1 = *(const short8*)&Pb[par][(16 * t + lr) * YSTR + 32 + lk * 8];
            acc[t] = MF(cf0, s0, (f32x4){0.f, 0.f, 0.f, 0.f});
            acc[t] = MF(cf1, s1, acc[t]);
        }
        float sAcl[4], el[4];
#pragma unroll
        for (int rr = 0; rr < 4; rr++) { sAcl[rr] = sAc2[par][16 * w + lk * 4 + rr]; el[rr] = __expf(sAcl[rr]); }
#pragma unroll
        for (int t = 0; t < 2; t++)
#pragma unroll
            for (int rr = 0; rr < 4; rr++) acc[t][rr] *= el[rr];
        // P2: G = C * B^T, mask/decay
        short* gw = Gs + w * 16 * YSTR;
#pragma unroll
        for (int t = 0; t < 4; t++) {
            short8 b0 = *(const short8*)&Bt[par][(16 * t + lr) * YSTR + lk * 8];
            short8 b1 = *(const short8*)&Bt[par][(16 * t + lr) * YSTR + 32 + lk * 8];
            f32x4 g = MF(cf0, b0, (f32x4){0.f, 0.f, 0.f, 0.f});
            g = MF(cf1, b1, g);
            int s = 16 * t + lr;
            float sAcs = sAc2[par][s], dts = sdt2[par][s];
#pragma unroll
            for (int rr = 0; rr < 4; rr++) {
                int l = 16 * w + lk * 4 + rr;
                float v = (s <= l) ? g[rr] * __expf(sAcl[rr] - sAcs) * dts : 0.f;
                gw[(lk * 4 + rr) * YSTR + s] = f2bits(v);
            }
        }
        // P3: Y += G * X
        short8 gf0 = *(const short8*)&gw[lr * YSTR + lk * 8];
        short8 gf1 = *(const short8*)&gw[lr * YSTR + 32 + lk * 8];
#pragma unroll
        for (int t = 0; t < 2; t++) {
            short8 x0 = *(const short8*)&Xt[par][(16 * t + lr) * YSTR + lk * 8];
            short8 x1 = *(const short8*)&Xt[par][(16 * t + lr) * YSTR + 32 + lk * 8];
            acc[t] = MF(gf0, x0, acc[t]);
            acc[t] = MF(gf1, x1, acc[t]);
        }
        // Y epilogue (+D*x) into Ct[par]'s own wave rows; coalesced z-gate
#pragma unroll
        for (int t = 0; t < 2; t++) {
#pragma unroll
            for (int rr = 0; rr < 4; rr++) {
                int p = 16 * t + lr;
                int l = 16 * w + lk * 4 + rr;
                float y = acc[t][rr] + Dh * bits2f(Xt[par][p * YSTR + l]);
                Ct[par][l * YSTR + p] = f2bits(y);
            }
        }
        {
            short8 y8 = *(const short8*)&Ct[par][zl * YSTR + zp];
            short* zpp = (short*)zx + (size_t)(rows0 + zl) * N1 + xcol + zp;
            short8 o;
#pragma unroll
            for (int j = 0; j < 8; j++) {
                float z = bits2f(zcur[j]);
                o[j] = f2bits(bits2f(y8[j]) * (z * sigmoidf_(z)));
            }
            *(short8*)zpp = o;
        }
        if (i + 1 < 4) scat(nb);
        __syncthreads();
    }
}

extern "C" void kernel_launch(void* const* d_in, const int* in_sizes, int n_in,
                              void* d_out, int out_size, void* d_ws, size_t ws_size,
                              hipStream_t stream) {
    const float* u       = (const float*)d_in[0];
    const float* W_in    = (const float*)d_in[1];
    const float* conv_w  = (const float*)d_in[2];
    const float* conv_b  = (const float*)d_in[3];
    const float* dt_bias = (const float*)d_in[4];
    const float* A_log   = (const float*)d_in[5];
    const float* Dp      = (const float*)d_in[6];
    const float* norm_w  = (const float*)d_in[7];
    const float* W_out   = (const float*)d_in[8];
    float* out = (float*)d_out;

    // Workspace layout (~175 MiB total):
    char* ws = (char*)d_ws;
    bf16* zx     = (bf16*)ws;  ws += (size_t)MTOT * N1 * 2;       // 69.2 MB
    bf16* xbc    = (bf16*)ws;  ws += (size_t)MTOT * CONVD * 2;    // 35.7 MB
    bf16* wout_b = (bf16*)ws;  ws += (size_t)DMODEL * DINNER * 2; // 4 MB
    float* dtt   = (float*)ws; ws += (size_t)NH * MTOT * 4;       // 1 MB, [h][t]
    float* sAcw  = (float*)ws; ws += (size_t)NH * MTOT * 4;       // 1 MB
    float* sfvw  = (float*)ws; ws += (size_t)NH * MTOT * 4;       // 1 MB
    float* etotw = (float*)ws; ws += 64 * 1024;                   // 16 KB (padded)
    float* SL    = (float*)ws; ws += (size_t)256 * NCH * 32 * 64 * 4; // 67.1 MB

    // d_out (32 MiB) doubles as scratch for GEMM1 inputs only.
    bf16* u_b   = (bf16*)d_out;                                      // 16 MB
    bf16* win_b = (bf16*)((char*)d_out + (size_t)MTOT * DMODEL * 2); // 8.25 MB

    k_prep<<<MTOT / 8, 256, 0, stream>>>(u, W_in, dt_bias, u_b, dtt);
    k_dts<<<dim3(NH, BSZ), 256, 0, stream>>>(dtt, A_log, sAcw, sfvw, etotw);
    k_cvt2<<<((N1 * DMODEL + DMODEL * DINNER) / 4 + 255) / 256, 256, 0, stream>>>(
        W_in, W_out, norm_w, win_b, wout_b);

    // GEMM1: 256x192 tiles, 8-phase counted-vmcnt pipeline
    k_g1<<<dim3(N1 / 192, MTOT / 256), 512, 0, stream>>>(u_b, win_b, zx);

    k_conv<<<(MTOT * CONVD / 4 + 255) / 256, 256, 0, stream>>>(zx, conv_w, conv_b, xbc);

    // SSD as 3 passes: chunk-local states -> tiny serial scan -> Y/gate
    k_ssda<<<dim3(2, NH, BSZ * 8), 256, 0, stream>>>(xbc, sfvw, SL);
    k_ssdb<<<256, 256, 0, stream>>>(SL, etotw, zx);
    k_ssdc<<<dim3(2, NH, BSZ * 8), 256, 0, stream>>>(xbc, dtt, sAcw, Dp, zx);

    // GEMM2 (+RMS): 256x128 tiles, 3-buffer counted-vmcnt pipeline, zero tail
    k_g2<<<dim3(DMODEL / 128, MTOT / 256), 512, 0, stream>>>(zx, wout_b, out);
}

// Round 6
// 374.364 us; speedup vs baseline: 1.0587x; 1.0587x over previous
//
#include <hip/hip_runtime.h>
#include <hip/hip_bf16.h>

#define BSZ 4
#define SEQ 2048
#define DMODEL 1024
#define DINNER 2048
#define DSTATE 64
#define NH 32
#define HD 64
#define CKL 64            // chunk length
#define NCH 32            // chunks per sequence
#define CONVD 2176
#define DPROJ 4256
#define N1 4224           // GEMM1 N = DINNER + CONVD = 22*192
#define MTOT 8192         // BSZ*SEQ
#define YSTR 72           // LDS row stride (bf16): 144 B, keeps 16B alignment
#define CVTB 6272         // blocks of k_pre2 doing weight-convert role

typedef __hip_bfloat16 bf16;
typedef __attribute__((ext_vector_type(8))) short short8;   // 8 bf16 (4 VGPRs)
typedef __attribute__((ext_vector_type(4))) short short4_;  // 8 bytes
typedef __attribute__((ext_vector_type(4))) float f32x4;

__device__ __forceinline__ float sigmoidf_(float x) { return 1.0f / (1.0f + __expf(-x)); }
__device__ __forceinline__ float bits2f(short s) { return __uint_as_float(((unsigned)(unsigned short)s) << 16); }
__device__ __forceinline__ short f2bits(float f) {
    bf16 h = __float2bfloat16(f);
    return *reinterpret_cast<short*>(&h);
}

__device__ __forceinline__ void gl_lds16(const bf16* g, bf16* l) {
    __builtin_amdgcn_global_load_lds((const __attribute__((address_space(1))) void*)g,
                                     (__attribute__((address_space(3))) void*)l, 16, 0, 0);
}

__device__ __forceinline__ f32x4 MF(short8 a, short8 b, f32x4 c) {
    return __builtin_amdgcn_mfma_f32_16x16x32_bf16(a, b, c, 0, 0, 0);
}

// counted s_waitcnt vmcnt(N); "memory" clobber = compiler fence.
template<int N> __device__ __forceinline__ void vmw() {
    if constexpr (N == 0)      asm volatile("s_waitcnt vmcnt(0)" ::: "memory");
    else if constexpr (N == 3) asm volatile("s_waitcnt vmcnt(3)" ::: "memory");
    else if constexpr (N == 6) asm volatile("s_waitcnt vmcnt(6)" ::: "memory");
    else                       asm volatile("s_waitcnt vmcnt(15)" ::: "memory");
}

// XCD-chunked locality swizzle (bijective: nwg % 8 == 0 for GEMM grids).
__device__ __forceinline__ void swzx(int& bx, int& by) {
    int nx = gridDim.x;
    int nwg = nx * gridDim.y;
    int Lr = blockIdx.y * nx + blockIdx.x;
    int L = (Lr & 7) * (nwg >> 3) + (Lr >> 3);   // contiguous chunk per XCD
    int GSZ = nx * 8;
    int g = L / GSZ, r = L - g * GSZ;
    bx = r % nx;
    by = g * 8 + r / nx;
}

// ---------------- merged: weight converts + u->bf16 + dt projection ----------------
// blocks [0, CVTB): convert W_in (bf16) and W_out*norm_w (bf16), 4 elems/thread.
// blocks [CVTB, CVTB+1024): per-8-rows u convert + dt GEMV (softplus), as before.
__global__ __launch_bounds__(256) void k_pre2(const float* __restrict__ u, const float* __restrict__ W_in,
                                              const float* __restrict__ dt_bias,
                                              const float* __restrict__ W_out, const float* __restrict__ nw,
                                              bf16* __restrict__ u_b, float* __restrict__ dtt,
                                              bf16* __restrict__ win_b, bf16* __restrict__ wout_b) {
    __shared__ __align__(16) float us[8 * DMODEL];
    const int tid = threadIdx.x;
    if (blockIdx.x < CVTB) {
        int g = (blockIdx.x * 256 + tid) * 4;
        if (g < N1 * DMODEL) {
            f32x4 f = *(const f32x4*)&W_in[g];
            short4_ o;
#pragma unroll
            for (int j = 0; j < 4; j++) o[j] = f2bits(f[j]);
            *(short4_*)&win_b[g] = o;
        } else if (g < N1 * DMODEL + DMODEL * DINNER) {
            int g2 = g - N1 * DMODEL;
            f32x4 f = *(const f32x4*)&W_out[g2];
            f32x4 w = *(const f32x4*)&nw[g2 & (DINNER - 1)];
            short4_ o;
#pragma unroll
            for (int j = 0; j < 4; j++) o[j] = f2bits(f[j] * w[j]);
            *(short4_*)&wout_b[g2] = o;
        }
        return;
    }
    const int t0 = (blockIdx.x - CVTB) * 8;
    const float* ur = u + (size_t)t0 * DMODEL;
    bf16* ub = u_b + (size_t)t0 * DMODEL;
#pragma unroll
    for (int i = 0; i < 8; i++) {
        int idx = (i * 256 + tid) * 4;
        f32x4 v = *(const f32x4*)&ur[idx];
        *(f32x4*)&us[idx] = v;
        short4_ o;
#pragma unroll
        for (int j = 0; j < 4; j++) o[j] = f2bits(v[j]);
        *(short4_*)&ub[idx] = o;
    }
    __syncthreads();
    const int h = tid >> 3, sub = tid & 7;
    const float* wr = W_in + (size_t)(DPROJ - NH + h) * DMODEL;
    float s[8] = {};
    for (int k = sub * 4; k < DMODEL; k += 32) {
        f32x4 w4 = *(const f32x4*)&wr[k];
#pragma unroll
        for (int rr = 0; rr < 8; rr++) {
            f32x4 u4 = *(const f32x4*)&us[rr * DMODEL + k];
            s[rr] += u4[0] * w4[0] + u4[1] * w4[1] + u4[2] * w4[2] + u4[3] * w4[3];
        }
    }
#pragma unroll
    for (int rr = 0; rr < 8; rr++) {
        s[rr] += __shfl_down(s[rr], 4, 8);
        s[rr] += __shfl_down(s[rr], 2, 8);
        s[rr] += __shfl_down(s[rr], 1, 8);
    }
    if (sub == 0) {
        float bh = dt_bias[h];
#pragma unroll
        for (int rr = 0; rr < 8; rr++) {
            float x = s[rr] + bh;
            dtt[(size_t)h * MTOT + t0 + rr] = (x > 20.f) ? x : log1pf(__expf(x));
        }
    }
}

// Shared phase scaffolding for the counted-vmcnt GEMMs.
#define BARWAIT()                                           \
    __builtin_amdgcn_s_barrier();                           \
    asm volatile("s_waitcnt lgkmcnt(0)" ::: "memory");      \
    __builtin_amdgcn_sched_barrier(0);                      \
    __builtin_amdgcn_s_setprio(1)
#define ENDPH()                                             \
    __builtin_amdgcn_s_setprio(0);                          \
    __builtin_amdgcn_s_barrier()

// =====================================================================
// GEMM1: zx[8192][4224] = A[8192][1024] * W[4224][1024]^T  (bf16 out)
// BM=256 x BN=192, BK=64, NT=16. 8 waves (2M x 4N), wave 128x48.
// 2 LDS buffers (112 KiB). 8 phases per 2 K-tiles, 12 MFMA/cluster.
// =====================================================================
__global__ __launch_bounds__(512, 2) void k_g1(const bf16* __restrict__ Ap,
                                               const bf16* __restrict__ Wp,
                                               bf16* __restrict__ Cp) {
    __shared__ __align__(16) short sA[2][16384];  // [buf][256][64]
    __shared__ __align__(16) short sB[2][12288];  // [buf][192][64]
    const int tid = threadIdx.x;
    const int lane = tid & 63, w = tid >> 6;
    const int wm = w >> 2, wn = w & 3;
    const int lr = lane & 15, lk = lane >> 4;
    int bx, by; swzx(bx, by);
    const int m0 = by * 256, n0 = bx * 192;
    const int ld = DMODEL;

    const int r8 = tid >> 3;
    const int c8 = ((tid & 7) ^ (r8 & 7)) * 8;
    const bf16* pA = Ap + (size_t)(m0 + r8) * ld + c8;
    const bf16* pB = Wp + (size_t)(n0 + r8) * ld + c8;

    auto stA = [&](int d, int t) {
#pragma unroll
        for (int h = 0; h < 2; h++)
#pragma unroll
            for (int q = 0; q < 2; q++)
                gl_lds16(pA + (size_t)(h * 128 + q * 64) * ld + t * 64,
                         (bf16*)&sA[d][h * 8192 + q * 4096 + tid * 8]);
    };
    auto stB = [&](int d, int u, int t) {
        gl_lds16(pB + (size_t)(u * 64) * ld + t * 64,
                 (bf16*)&sB[d][u * 4096 + tid * 8]);
    };

    const int c0 = (lk ^ (lr & 7)) * 8;
    const int c1 = ((lk + 4) ^ (lr & 7)) * 8;
    const int aR = (wm * 128 + lr) * 64;
    const int bR = (wn * 48 + lr) * 64;

    f32x4 acc[8][3];
#pragma unroll
    for (int i = 0; i < 8; i++)
#pragma unroll
        for (int j = 0; j < 3; j++) acc[i][j] = (f32x4){0.f, 0.f, 0.f, 0.f};
    short8 bfr[3][2], af[2][2];

#define RDA1(D, I)                                                   \
    af[0][0] = *(const short8*)&sA[D][aR + (I) * 1024 + c0];         \
    af[0][1] = *(const short8*)&sA[D][aR + (I) * 1024 + c1];         \
    af[1][0] = *(const short8*)&sA[D][aR + (I + 1) * 1024 + c0];     \
    af[1][1] = *(const short8*)&sA[D][aR + (I + 1) * 1024 + c1]
#define RDB1(D)                                                      \
    _Pragma("unroll")                                                \
    for (int jn = 0; jn < 3; ++jn) {                                 \
        bfr[jn][0] = *(const short8*)&sB[D][bR + jn * 1024 + c0];    \
        bfr[jn][1] = *(const short8*)&sB[D][bR + jn * 1024 + c1];    \
    }
#define MM1(I)                                                       \
    _Pragma("unroll")                                                \
    for (int hh = 0; hh < 2; ++hh) {                                 \
        _Pragma("unroll")                                            \
        for (int jn = 0; jn < 3; ++jn) {                             \
            acc[I][jn]     = MF(af[0][hh], bfr[jn][hh], acc[I][jn]); \
            acc[I + 1][jn] = MF(af[1][hh], bfr[jn][hh], acc[I + 1][jn]); \
        }                                                            \
    }

    stB(0, 0, 0); stB(0, 1, 0); stB(0, 2, 0); stA(0, 0);
    stB(1, 0, 1); stB(1, 1, 1); stB(1, 2, 1);
    vmw<3>();
    __builtin_amdgcn_s_barrier();

    for (int t0 = 0; t0 < 16; t0 += 2) {
        const int t1 = t0 + 1, t2 = t0 + 2, t3 = t0 + 3;
        const bool more = (t2 < 16);
        // P1
        RDB1(0); RDA1(0, 0);
        stA(1, t1);
        BARWAIT(); MM1(0); ENDPH();
        // P2
        RDA1(0, 2); if (more) stB(0, 0, t2);
        BARWAIT(); MM1(2); ENDPH();
        // P3
        RDA1(0, 4); if (more) stB(0, 1, t2);
        BARWAIT(); MM1(4); ENDPH();
        // P4
        RDA1(0, 6); if (more) stB(0, 2, t2);
        BARWAIT(); MM1(6);
        __builtin_amdgcn_s_setprio(0);
        if (more) vmw<3>(); else vmw<0>();
        __builtin_amdgcn_s_barrier();
        // P5
        RDB1(1); RDA1(1, 0);
        if (more) stA(0, t2);
        BARWAIT(); MM1(0); ENDPH();
        // P6
        RDA1(1, 2); if (more) stB(1, 0, t3);
        BARWAIT(); MM1(2); ENDPH();
        // P7
        RDA1(1, 4); if (more) stB(1, 1, t3);
        BARWAIT(); MM1(4); ENDPH();
        // P8
        RDA1(1, 6); if (more) stB(1, 2, t3);
        BARWAIT(); MM1(6);
        __builtin_amdgcn_s_setprio(0);
        if (more) vmw<3>();
        __builtin_amdgcn_s_barrier();
    }
#undef RDA1
#undef RDB1
#undef MM1

#pragma unroll
    for (int im = 0; im < 8; im++) {
        int row = m0 + wm * 128 + im * 16 + lk * 4;
#pragma unroll
        for (int jn = 0; jn < 3; jn++) {
            int col = n0 + wn * 48 + jn * 16 + lr;
            bf16* cp = Cp + (size_t)row * N1 + col;
#pragma unroll
            for (int rr = 0; rr < 4; rr++) cp[(size_t)rr * N1] = __float2bfloat16(acc[im][jn][rr]);
        }
    }
}

// =====================================================================
// GEMM2 (+fused RMSNorm): out[8192][1024] = A(zx)[8192][2048] * W[1024][2048]^T
// BM=256 x BN=128, BK=64, NT=32. 8 waves (4M x 2N), wave 64x64.
// 3 LDS buffers (144 KiB), counted vmcnt(6)/tile, 2 phases/tile.
// =====================================================================
__global__ __launch_bounds__(512, 2) void k_g2(const bf16* __restrict__ Ap,
                                               const bf16* __restrict__ Wp,
                                               float* __restrict__ Cp) {
    __shared__ __align__(16) short sA[3][16384];  // [buf][256][64]
    __shared__ __align__(16) short sB[3][8192];   // [buf][128][64]
    __shared__ float rsrow[256];
    const int tid = threadIdx.x;
    const int lane = tid & 63, w = tid >> 6;
    const int wm = w >> 1, wn = w & 1;
    const int lr = lane & 15, lk = lane >> 4;
    int bx, by; swzx(bx, by);
    const int m0 = by * 256, n0 = bx * 128;
    const int lda = N1, ldb = DINNER;

    const int r8 = tid >> 3;
    const int c8 = ((tid & 7) ^ (r8 & 7)) * 8;
    const bf16* pA = Ap + (size_t)(m0 + r8) * lda + c8;
    const bf16* pB = Wp + (size_t)(n0 + r8) * ldb + c8;

    auto stA = [&](int d, int t) {
#pragma unroll
        for (int h = 0; h < 2; h++)
#pragma unroll
            for (int q = 0; q < 2; q++)
                gl_lds16(pA + (size_t)(h * 128 + q * 64) * lda + t * 64,
                         (bf16*)&sA[d][h * 8192 + q * 4096 + tid * 8]);
    };
    auto stB = [&](int d, int t) {
#pragma unroll
        for (int q = 0; q < 2; q++)
            gl_lds16(pB + (size_t)(q * 64) * ldb + t * 64,
                     (bf16*)&sB[d][q * 4096 + tid * 8]);
    };

    const int c0 = (lk ^ (lr & 7)) * 8;
    const int c1 = ((lk + 4) ^ (lr & 7)) * 8;
    const int aR = (wm * 64 + lr) * 64;
    const int bR = (wn * 64 + lr) * 64;

    f32x4 acc[4][4];
#pragma unroll
    for (int i = 0; i < 4; i++)
#pragma unroll
        for (int j = 0; j < 4; j++) acc[i][j] = (f32x4){0.f, 0.f, 0.f, 0.f};
    float ssq[4] = {0.f, 0.f, 0.f, 0.f};
    short8 bfr[4][2], af[2][2];

#define RDA2(D, I)                                                   \
    af[0][0] = *(const short8*)&sA[D][aR + (I) * 1024 + c0];         \
    af[0][1] = *(const short8*)&sA[D][aR + (I) * 1024 + c1];         \
    af[1][0] = *(const short8*)&sA[D][aR + (I + 1) * 1024 + c0];     \
    af[1][1] = *(const short8*)&sA[D][aR + (I + 1) * 1024 + c1]
#define RDB2(D)                                                      \
    _Pragma("unroll")                                                \
    for (int jn = 0; jn < 4; ++jn) {                                 \
        bfr[jn][0] = *(const short8*)&sB[D][bR + jn * 1024 + c0];    \
        bfr[jn][1] = *(const short8*)&sB[D][bR + jn * 1024 + c1];    \
    }
#define MM2(I)                                                       \
    _Pragma("unroll")                                                \
    for (int hh = 0; hh < 2; ++hh) {                                 \
        _Pragma("unroll")                                            \
        for (int jn = 0; jn < 4; ++jn) {                             \
            acc[I][jn]     = MF(af[0][hh], bfr[jn][hh], acc[I][jn]); \
            acc[I + 1][jn] = MF(af[1][hh], bfr[jn][hh], acc[I + 1][jn]); \
        }                                                            \
    }
#define SSQ2(I)                                                      \
    _Pragma("unroll")                                                \
    for (int hh = 0; hh < 2; ++hh)                                   \
        _Pragma("unroll")                                            \
        for (int e = 0; e < 8; ++e) {                                \
            float v0 = bits2f(af[0][hh][e]), v1 = bits2f(af[1][hh][e]); \
            ssq[I] += v0 * v0; ssq[I + 1] += v1 * v1;                \
        }

    stB(0, 0); stA(0, 0);
    stB(1, 1); stA(1, 1);
    vmw<6>();
    __builtin_amdgcn_s_barrier();

    int rb = 0, sb = 2;
    for (int t = 0; t < 32; ++t) {
        const bool more = (t + 2 < 32);
        // Pa
        RDB2(rb); RDA2(rb, 0);
        if (more) stB(sb, t + 2);
        BARWAIT(); MM2(0); SSQ2(0); ENDPH();
        // Pb
        RDA2(rb, 2);
        if (more) stA(sb, t + 2);
        BARWAIT(); MM2(2); SSQ2(2);
        __builtin_amdgcn_s_setprio(0);
        if (more) vmw<6>(); else if (t + 1 < 32) vmw<0>();
        __builtin_amdgcn_s_barrier();
        rb = (rb == 2) ? 0 : rb + 1;
        sb = (sb == 2) ? 0 : sb + 1;
    }
#undef RDA2
#undef RDB2
#undef MM2
#undef SSQ2

#pragma unroll
    for (int im = 0; im < 4; im++) {
        float s = ssq[im];
        s += __shfl_down(s, 32);
        s += __shfl_down(s, 16);
        if (lane < 16) rsrow[wm * 64 + im * 16 + lane] = rsqrtf(s * (1.0f / DINNER) + 1e-5f);
    }
    __syncthreads();
#pragma unroll
    for (int im = 0; im < 4; im++) {
        int rl = wm * 64 + im * 16 + lk * 4;
        int row = m0 + rl;
#pragma unroll
        for (int rr = 0; rr < 4; rr++) {
            float s = rsrow[rl + rr];
#pragma unroll
            for (int jn = 0; jn < 4; jn++) {
                int col = n0 + wn * 64 + jn * 16 + lr;
                Cp[(size_t)(row + rr) * DMODEL + col] = acc[im][jn][rr] * s;
            }
        }
    }
}

// ---------------- depthwise causal conv (width 4) + bias + SiLU ----------------
// 4 rows x 4 channels per thread: 7 tap-row loads produce 4 output rows,
// cutting zx-tail read traffic 4x -> 1.75x (143 MB -> 62 MB).
__global__ __launch_bounds__(256) void k_conv(const bf16* __restrict__ zx, const float* __restrict__ cw,
                                              const float* __restrict__ cb, bf16* __restrict__ xbc) {
    const int g = blockIdx.x * 256 + threadIdx.x;     // 0 .. 2048*544-1
    const int c0 = (g % 544) * 4;
    const int t0 = (g / 544) * 4;
    const int s0 = t0 & (SEQ - 1);
    const short* base = (const short*)(zx + (size_t)t0 * N1 + DINNER + c0);
    f32x4 w0 = *(const f32x4*)&cw[(c0 + 0) * 4];
    f32x4 w1 = *(const f32x4*)&cw[(c0 + 1) * 4];
    f32x4 w2 = *(const f32x4*)&cw[(c0 + 2) * 4];
    f32x4 w3 = *(const f32x4*)&cw[(c0 + 3) * 4];
    f32x4 bias = *(const f32x4*)&cb[c0];
    short4_ v[7];
#pragma unroll
    for (int o = 0; o < 7; o++) {
        if (s0 + o - 3 >= 0) v[o] = *(const short4_*)(base + (long)(o - 3) * N1);
        else v[o] = (short4_){0, 0, 0, 0};
    }
#pragma unroll
    for (int j = 0; j < 4; j++) {
        f32x4 a = bias;
#pragma unroll
        for (int k = 0; k < 4; k++) {
            short4_ x = v[j + k];                      // row t0 + j + k - 3
            a[0] += bits2f(x[0]) * w0[k];
            a[1] += bits2f(x[1]) * w1[k];
            a[2] += bits2f(x[2]) * w2[k];
            a[3] += bits2f(x[3]) * w3[k];
        }
        short4_ o_;
#pragma unroll
        for (int jj = 0; jj < 4; jj++) o_[jj] = f2bits(a[jj] * sigmoidf_(a[jj]));
        *(short4_*)((short*)xbc + (size_t)(t0 + j) * CONVD + c0) = o_;
    }
}

// ---------------- fused SSD scan: single barrier/chunk, parity double-buffered tiles ----------------
__global__ __launch_bounds__(256) void k_ssd(const bf16* __restrict__ xbc, const float* __restrict__ dtt,
                                             const float* __restrict__ A_log, const float* __restrict__ Dp,
                                             bf16* __restrict__ zx) {
    __shared__ __align__(16) short Ct[2][64 * YSTR];  // C [l][n]; own-wave rows reused as Y [l][p]
    __shared__ __align__(16) short Bt[2][64 * YSTR];  // B [s][n]
    __shared__ __align__(16) short Bn[2][64 * YSTR];  // B^T [n][l]
    __shared__ __align__(16) short Xt[2][32 * YSTR];  // X^T [p][l]
    __shared__ __align__(16) short Sb[2][32 * YSTR];  // state bf16 [p][n] at chunk start
    __shared__ __align__(16) short Gs[4 * 16 * YSTR]; // per-wave G
    __shared__ __align__(16) float Sf[32 * 68];       // running state fp32 [p][n]
    __shared__ __align__(16) float sdt2[2][64], sAc2[2][64], sf2[2][64];
    __shared__ float set2[2];

    const int ph = blockIdx.x, h = blockIdx.y, b = blockIdx.z;
    const int tid = threadIdx.x;
    const int lane = tid & 63, w = tid >> 6;
    const int lr = lane & 15, lk = lane >> 4;
    const float Ah = -__expf(A_log[h]);
    const float Dh = Dp[h];
    const int xcol = h * HD + ph * 32;

    const int lrow = tid >> 2, c0 = (tid & 3) * 16, px = (tid & 3) * 8;
    const int zl = 16 * w + (lane >> 2), zp = (lane & 3) * 8;

    short8 rC0, rC1, rB0, rB1, rX, rZ;
    float rdt;
    auto load_chunk = [&](int cc) {
        int rows0 = b * SEQ + cc * CKL;
        const short* rp = (const short*)(xbc + (size_t)(rows0 + lrow) * CONVD);
        rC0 = *(const short8*)&rp[DINNER + DSTATE + c0];
        rC1 = *(const short8*)&rp[DINNER + DSTATE + c0 + 8];
        rB0 = *(const short8*)&rp[DINNER + c0];
        rB1 = *(const short8*)&rp[DINNER + c0 + 8];
        rX  = *(const short8*)&rp[xcol + px];
        rZ  = *(const short8*)((const short*)zx + (size_t)(rows0 + zl) * N1 + xcol + zp);
        rdt = dtt[(size_t)h * MTOT + rows0 + lane];
    };
    auto scatter = [&](int buf) {
        *(short8*)&Ct[buf][lrow * YSTR + c0] = rC0;
        *(short8*)&Ct[buf][lrow * YSTR + c0 + 8] = rC1;
        *(short8*)&Bt[buf][lrow * YSTR + c0] = rB0;
        *(short8*)&Bt[buf][lrow * YSTR + c0 + 8] = rB1;
#pragma unroll
        for (int j = 0; j < 8; j++) {
            Bn[buf][(c0 + j) * YSTR + lrow] = rB0[j];
            Bn[buf][(c0 + 8 + j) * YSTR + lrow] = rB1[j];
            Xt[buf][(px + j) * YSTR + lrow] = rX[j];
        }
    };
    auto dtscan = [&](int buf) {
        if (tid < 64) {
            float dv = rdt;
            float v = Ah * dv;
#pragma unroll
            for (int d = 1; d < 64; d <<= 1) { float o = __shfl_up(v, d); if (tid >= d) v += o; }
            float tot = __shfl(v, 63);
            sdt2[buf][tid] = dv; sAc2[buf][tid] = v; sf2[buf][tid] = __expf(tot - v) * dv;
            if (tid == 63) set2[buf] = __expf(tot);
        }
    };

    for (int i = tid; i < 32 * 68; i += 256) Sf[i] = 0.f;
    for (int i = tid; i < 32 * YSTR; i += 256) Sb[0][i] = 0;
    load_chunk(0);
    scatter(0);
    dtscan(0);
    __syncthreads();

    for (int c = 0; c < NCH; c++) {
        const int par = c & 1, nb = par ^ 1;
        const int rows0 = b * SEQ + c * CKL;
        float etot = set2[par];
        short8 zcur = rZ;                 // z of chunk c (loaded last iteration / pre-loop)
        if (c + 1 < NCH) load_chunk(c + 1);

        short8 cf0 = *(const short8*)&Ct[par][(16 * w + lr) * YSTR + lk * 8];
        short8 cf1 = *(const short8*)&Ct[par][(16 * w + lr) * YSTR + 32 + lk * 8];
        // P1: Y_off = C * S0^T
        f32x4 acc[2];
#pragma unroll
        for (int t = 0; t < 2; t++) {
            short8 s0 = *(const short8*)&Sb[par][(16 * t + lr) * YSTR + lk * 8];
            short8 s1 = *(const short8*)&Sb[par][(16 * t + lr) * YSTR + 32 + lk * 8];
            acc[t] = MF(cf0, s0, (f32x4){0.f, 0.f, 0.f, 0.f});
            acc[t] = MF(cf1, s1, acc[t]);
        }
        float sAcl[4], el[4];
#pragma unroll
        for (int rr = 0; rr < 4; rr++) { sAcl[rr] = sAc2[par][16 * w + lk * 4 + rr]; el[rr] = __expf(sAcl[rr]); }
#pragma unroll
        for (int t = 0; t < 2; t++)
#pragma unroll
            for (int rr = 0; rr < 4; rr++) acc[t][rr] *= el[rr];
        // P2: G = C * B^T, mask/decay, wave-private LDS round-trip
        short* gw = Gs + w * 16 * YSTR;
#pragma unroll
        for (int t = 0; t < 4; t++) {
            short8 b0 = *(const short8*)&Bt[par][(16 * t + lr) * YSTR + lk * 8];
            short8 b1 = *(const short8*)&Bt[par][(16 * t + lr) * YSTR + 32 + lk * 8];
            f32x4 g = MF(cf0, b0, (f32x4){0.f, 0.f, 0.f, 0.f});
            g = MF(cf1, b1, g);
            int s = 16 * t + lr;
            float sAcs = sAc2[par][s], dts = sdt2[par][s];
#pragma unroll
            for (int rr = 0; rr < 4; rr++) {
                int l = 16 * w + lk * 4 + rr;
                float v = (s <= l) ? g[rr] * __expf(sAcl[rr] - sAcs) * dts : 0.f;
                gw[(lk * 4 + rr) * YSTR + s] = f2bits(v);
            }
        }
        // P3: Y += G * X
        short8 gf0 = *(const short8*)&gw[lr * YSTR + lk * 8];
        short8 gf1 = *(const short8*)&gw[lr * YSTR + 32 + lk * 8];
#pragma unroll
        for (int t = 0; t < 2; t++) {
            short8 x0 = *(const short8*)&Xt[par][(16 * t + lr) * YSTR + lk * 8];
            short8 x1 = *(const short8*)&Xt[par][(16 * t + lr) * YSTR + 32 + lk * 8];
            acc[t] = MF(gf0, x0, acc[t]);
            acc[t] = MF(gf1, x1, acc[t]);
        }
        // P4: Snew = (Xt*sf) * Bn^T ; Sf = Sf*etot + Snew ; Sb[nb] = bf16(Sf)
        {
            int pw = w & 1, nh2 = w >> 1;
            short8 xt0 = *(const short8*)&Xt[par][(16 * pw + lr) * YSTR + lk * 8];
            short8 xt1 = *(const short8*)&Xt[par][(16 * pw + lr) * YSTR + 32 + lk * 8];
            f32x4 sa0 = *(const f32x4*)&sf2[par][lk * 8];
            f32x4 sa1 = *(const f32x4*)&sf2[par][lk * 8 + 4];
            f32x4 sb0 = *(const f32x4*)&sf2[par][32 + lk * 8];
            f32x4 sb1 = *(const f32x4*)&sf2[par][32 + lk * 8 + 4];
            short8 xd0, xd1;
#pragma unroll
            for (int j = 0; j < 4; j++) {
                xd0[j]     = f2bits(bits2f(xt0[j])     * sa0[j]);
                xd0[4 + j] = f2bits(bits2f(xt0[4 + j]) * sa1[j]);
                xd1[j]     = f2bits(bits2f(xt1[j])     * sb0[j]);
                xd1[4 + j] = f2bits(bits2f(xt1[4 + j]) * sb1[j]);
            }
#pragma unroll
            for (int j = 0; j < 2; j++) {
                int nt = 2 * nh2 + j;
                short8 b0 = *(const short8*)&Bn[par][(16 * nt + lr) * YSTR + lk * 8];
                short8 b1 = *(const short8*)&Bn[par][(16 * nt + lr) * YSTR + 32 + lk * 8];
                f32x4 sacc = MF(xd0, b0, (f32x4){0.f, 0.f, 0.f, 0.f});
                sacc = MF(xd1, b1, sacc);
#pragma unroll
                for (int rr = 0; rr < 4; rr++) {
                    int n = 16 * nt + lr;
                    int p = 16 * pw + lk * 4 + rr;
                    float nv = Sf[p * 68 + n] * etot + sacc[rr];
                    Sf[p * 68 + n] = nv;
                    Sb[nb][p * YSTR + n] = f2bits(nv);
                }
            }
        }
        // Y epilogue (+D*x) into Ct[par]'s own wave rows; coalesced z-gate
#pragma unroll
        for (int t = 0; t < 2; t++) {
#pragma unroll
            for (int rr = 0; rr < 4; rr++) {
                int p = 16 * t + lr;
                int l = 16 * w + lk * 4 + rr;
                float y = acc[t][rr] + Dh * bits2f(Xt[par][p * YSTR + l]);
                Ct[par][l * YSTR + p] = f2bits(y);
            }
        }
        {
            short8 y8 = *(const short8*)&Ct[par][zl * YSTR + zp];
            short* zpp = (short*)zx + (size_t)(rows0 + zl) * N1 + xcol + zp;
            short8 o;
#pragma unroll
            for (int j = 0; j < 8; j++) {
                float z = bits2f(zcur[j]);
                o[j] = f2bits(bits2f(y8[j]) * (z * sigmoidf_(z)));
            }
            *(short8*)zpp = o;
        }
        // stage chunk c+1 (off critical path: independent of this chunk's compute)
        if (c + 1 < NCH) {
            scatter(nb);
            dtscan(nb);
        }
        __syncthreads();
    }
}

extern "C" void kernel_launch(void* const* d_in, const int* in_sizes, int n_in,
                              void* d_out, int out_size, void* d_ws, size_t ws_size,
                              hipStream_t stream) {
    const float* u       = (const float*)d_in[0];
    const float* W_in    = (const float*)d_in[1];
    const float* conv_w  = (const float*)d_in[2];
    const float* conv_b  = (const float*)d_in[3];
    const float* dt_bias = (const float*)d_in[4];
    const float* A_log   = (const float*)d_in[5];
    const float* Dp      = (const float*)d_in[6];
    const float* norm_w  = (const float*)d_in[7];
    const float* W_out   = (const float*)d_in[8];
    float* out = (float*)d_out;

    // Workspace layout (~108 MiB total):
    char* ws = (char*)d_ws;
    bf16* zx     = (bf16*)ws;  ws += (size_t)MTOT * N1 * 2;       // 69.2 MB
    bf16* xbc    = (bf16*)ws;  ws += (size_t)MTOT * CONVD * 2;    // 35.7 MB
    bf16* wout_b = (bf16*)ws;  ws += (size_t)DMODEL * DINNER * 2; // 4 MB
    float* dtt   = (float*)ws; ws += (size_t)NH * MTOT * 4;       // 1 MB, [h][t]

    // d_out (32 MiB) doubles as scratch for GEMM1 inputs only.
    bf16* u_b   = (bf16*)d_out;                                      // 16 MB
    bf16* win_b = (bf16*)((char*)d_out + (size_t)MTOT * DMODEL * 2); // 8.25 MB

    // merged weight-convert + u-prep + dt projection (one launch)
    k_pre2<<<CVTB + MTOT / 8, 256, 0, stream>>>(u, W_in, dt_bias, W_out, norm_w,
                                                u_b, dtt, win_b, wout_b);

    // GEMM1: 256x192 tiles, 8-phase counted-vmcnt pipeline
    k_g1<<<dim3(N1 / 192, MTOT / 256), 512, 0, stream>>>(u_b, win_b, zx);

    // depthwise conv, 4 rows/thread
    k_conv<<<(MTOT / 4) * (CONVD / 4) / 256, 256, 0, stream>>>(zx, conv_w, conv_b, xbc);

    // fused SSD scan (parity double-buffered, best measured variant)
    k_ssd<<<dim3(2, NH, BSZ), 256, 0, stream>>>(xbc, dtt, A_log, Dp, zx);

    // GEMM2 (+RMS): 256x128 tiles, 3-buffer counted-vmcnt pipeline, zero tail
    k_g2<<<dim3(DMODEL / 128, MTOT / 256), 512, 0, stream>>>(zx, wout_b, out);
}